// Round 2
// baseline (172.596 us; speedup 1.0000x reference)
//
#include <hip/hip_runtime.h>

// Replicate XLA:CPU's exact f32 rounding: no mul+add fusion anywhere
// (hipcc default is -ffp-contract=fast; XLA:CPU emits separate fmul/fadd
// with xla_cpu_enable_fast_math=false).
#pragma clang fp contract(off)

#define TPB 256

// ---------------------------------------------------------------------------
// Threefry-2x32, key = (0, 42). Partitionable counting (jax default since
// 0.4.36): element j <- block(x0 = hi = 0, x1 = lo = j); 32-bit draw is
// bits1 ^ bits2 (XOR of both output lanes) per _threefry_random_bits_partitionable.
// ---------------------------------------------------------------------------
__device__ __forceinline__ uint32_t rotl32(uint32_t x, uint32_t n) {
  return (x << n) | (x >> (32u - n));
}

__device__ __forceinline__ uint32_t threefry_draw32(uint32_t j) {
  const uint32_t ks1 = 42u;
  const uint32_t ks2 = 0x1BD11BDAu ^ 42u;  // 0x1BD11BF0
  uint32_t x0 = 0u;        // counts_hi = 0 (+ ks0 = 0)
  uint32_t x1 = j + ks1;   // counts_lo + ks1

#define TFR(r) { x0 += x1; x1 = rotl32(x1, r); x1 ^= x0; }
  TFR(13u) TFR(15u) TFR(26u) TFR(6u)   x0 += ks1; x1 += ks2 + 1u;
  TFR(17u) TFR(29u) TFR(16u) TFR(24u)  x0 += ks2; x1 += 0u  + 2u;
  TFR(13u) TFR(15u) TFR(26u) TFR(6u)   x0 += 0u;  x1 += ks1 + 3u;
  TFR(17u) TFR(29u) TFR(16u) TFR(24u)  x0 += ks1; x1 += ks2 + 4u;
  TFR(13u) TFR(15u) TFR(26u) TFR(6u)   x0 += ks2; x1 += 0u  + 5u;
#undef TFR
  return x0 ^ x1;  // bits1 ^ bits2, truncated to u32
}

// ---------------------------------------------------------------------------
// Bit-exact replica of XLA:CPU GenerateVF32Log (Cephes/Eigen plog), separate
// mul/add (no FMA). Valid for positive normal inputs (all we pass).
// ---------------------------------------------------------------------------
__device__ __forceinline__ float xla_logf(float xin) {
  uint32_t bits = __float_as_uint(xin);
  int emm0 = (int)(bits >> 23) - 0x7f;
  float m = __uint_as_float((bits & 0x007fffffu) | 0x3f000000u);  // [0.5, 1)
  float e = (float)emm0 + 1.0f;

  bool mask = m < 0.707106781186547524f;
  float tmp = mask ? m : 0.0f;
  m = m - 1.0f;
  e = e - (mask ? 1.0f : 0.0f);
  m = m + tmp;

  float x2 = m * m;
  float x3 = x2 * m;

  float y  =  7.0376836292e-2f * m + -1.1514610310e-1f;
  float y1 = -1.2420140846e-1f * m +  1.4249322787e-1f;
  float y2 =  2.0000714765e-1f * m + -2.4999993993e-1f;
  y  = y  * m +  1.1676998740e-1f;
  y1 = y1 * m + -1.6668057665e-1f;
  y2 = y2 * m +  3.3333331174e-1f;
  y  = y * x3 + y1;
  y  = y * x3 + y2;
  y  = y * x3;

  float t1 = -2.12194440e-4f * e;   // q1 * e
  float t2 = 0.5f * x2;
  y = y + t1;
  m = m - t2;
  float t3 = 0.693359375f * e;      // q2 * e
  m = m + y;
  m = m + t3;
  return m;
}

// ---------------------------------------------------------------------------
// Bit-exact replica of XLA:CPU GenerateVF32Exp (Cephes/Eigen pexp), no FMA.
// Inputs here are in [-~6, 0] (shifted logits) — no clamp/denormal concerns,
// but keep the full structure for fidelity.
// ---------------------------------------------------------------------------
__device__ __forceinline__ float xla_expf(float xin) {
  float xc = fminf(xin, 88.3762626647950f);
  xc = fmaxf(xc, -88.3762626647949f);

  float fx = floorf(xc * 1.44269504088896341f + 0.5f);
  float tmp = 0.693359375f * fx;        // cephes_exp_C1 * fx
  float z   = -2.12194440e-4f * fx;     // cephes_exp_C2 * fx
  float x = xc - tmp;
  x = x - z;
  z = x * x;

  float y = x * 1.9875691500e-4f + 1.3981999507e-3f;
  y = y * x + 8.3334519073e-3f;
  y = y * x + 4.1665795894e-2f;
  y = y * x + 1.6666665459e-1f;
  y = y * x + 5.0000001201e-1f;
  y = y * z + x;
  y = y + 1.0f;

  int n = (int)fx;
  float p2n = __uint_as_float((uint32_t)(n + 0x7f) << 23);
  return fmaxf(y * p2n, xin);
}

// uniform(tiny, 1) from raw bits -> standard gumbel, per JAX semantics.
__device__ __forceinline__ float ref_gumbel(uint32_t bits) {
  float f = __uint_as_float((bits >> 9) | 0x3f800000u) - 1.0f;  // [0, 1)
  float u = (f == 0.0f) ? 1.17549435082228750797e-38f : f;      // tiny (0x00800000)
  float l1 = xla_logf(u);
  float l2 = xla_logf(-l1);
  return -l2;
}

// ---------------------------------------------------------------------------
// One thread per batch element. logp = log_softmax(W.T + b) computed per
// block into LDS with the SAME Cephes exp/log rounding as the reference.
// Output (all f32, concat): u0[B] | beliefs[B][2] | log_cf[B][2].
// ---------------------------------------------------------------------------
__global__ void __launch_bounds__(TPB) sample_kernel(
    const int* __restrict__ cards, const float* __restrict__ W,
    const float* __restrict__ bvec,
    float* __restrict__ out_u0, float* __restrict__ out_beliefs,
    float* __restrict__ out_logcf, int B) {
  __shared__ float lp_s[6];
  if (threadIdx.x == 0) {
    for (int c = 0; c < 2; ++c) {
      float x0 = W[0 * 2 + c] + bvec[0];
      float x1 = W[1 * 2 + c] + bvec[1];
      float x2 = W[2 * 2 + c] + bvec[2];
      float mx = fmaxf(fmaxf(fmaxf(-__builtin_inff(), x0), x1), x2);  // reduce order
      float s0 = x0 - mx, s1 = x1 - mx, s2 = x2 - mx;
      float e0 = xla_expf(s0);
      float e1 = xla_expf(s1);
      float e2 = xla_expf(s2);
      float se = (e0 + e1) + e2;            // XLA sequential reduce order
      float lse = xla_logf(se);
      lp_s[c * 3 + 0] = s0 - lse;
      lp_s[c * 3 + 1] = s1 - lse;
      lp_s[c * 3 + 2] = s2 - lse;
    }
  }
  __syncthreads();

  int b = blockIdx.x * TPB + threadIdx.x;
  if (b >= B) return;

  float lp[6];
#pragma unroll
  for (int i = 0; i < 6; ++i) lp[i] = lp_s[i];

  uint32_t base = (uint32_t)b * 6u;

  int cf[2];
  float lcf[2];
#pragma unroll
  for (int c = 0; c < 2; ++c) {
    float s0 = ref_gumbel(threefry_draw32(base + (uint32_t)(c * 3) + 0u)) + lp[c * 3 + 0];
    float s1 = ref_gumbel(threefry_draw32(base + (uint32_t)(c * 3) + 1u)) + lp[c * 3 + 1];
    float s2 = ref_gumbel(threefry_draw32(base + (uint32_t)(c * 3) + 2u)) + lp[c * 3 + 2];
    int best_a = 0;
    float best = s0;
    if (s1 > best) { best = s1; best_a = 1; }  // strict > keeps first max (XLA tie rule)
    if (s2 > best) { best = s2; best_a = 2; }
    cf[c] = best_a;
    lcf[c] = lp[c * 3 + best_a];
  }

  int card = cards[b];
  int u0 = (card == 0) ? cf[0] : cf[1];
  float w0 = (u0 == cf[0]) ? 1.0f : 0.0f;
  float w1 = (u0 == cf[1]) ? 1.0f : 0.0f;
  float half_or_one = ((w0 + w1) > 1.5f) ? 0.5f : 1.0f;  // exact reciprocal

  out_u0[b] = (float)u0;
  reinterpret_cast<float2*>(out_beliefs)[b] = make_float2(w0 * half_or_one, w1 * half_or_one);
  reinterpret_cast<float2*>(out_logcf)[b]  = make_float2(lcf[0], lcf[1]);
}

extern "C" void kernel_launch(void* const* d_in, const int* in_sizes, int n_in,
                              void* d_out, int out_size, void* d_ws, size_t ws_size,
                              hipStream_t stream) {
  (void)n_in; (void)out_size; (void)d_ws; (void)ws_size;
  const int* cards = (const int*)d_in[0];   // (B,) int32
  const float* W   = (const float*)d_in[1]; // (3,2) f32 row-major
  const float* bv  = (const float*)d_in[2]; // (3,)  f32
  float* out = (float*)d_out;               // u0[B] | beliefs[B*2] | log_cf[B*2]

  int B = in_sizes[0];
  sample_kernel<<<(B + TPB - 1) / TPB, TPB, 0, stream>>>(
      cards, W, bv, out, out + (size_t)B, out + (size_t)3 * B, B);
}

// Round 3
// 168.259 us; speedup vs baseline: 1.0258x; 1.0258x over previous
//
#include <hip/hip_runtime.h>

// Replicate XLA:CPU's exact f32 rounding: no mul+add fusion anywhere
// (hipcc default is -ffp-contract=fast; XLA:CPU emits separate fmul/fadd
// with xla_cpu_enable_fast_math=false). Applies to packed ops too (blocks
// v_pk_fma formation).
#pragma clang fp contract(off)

#define TPB 256

typedef float f32x2 __attribute__((ext_vector_type(2)));

// ---------------------------------------------------------------------------
// Threefry-2x32, key = (0, 42). Partitionable counting: element j <- block
// (x0 = hi = 0, x1 = lo = j); 32-bit draw = bits1 ^ bits2 (verified round 2).
// Pure scalar int ARX — no packing possible; rotl lowers to v_alignbit_b32.
// ---------------------------------------------------------------------------
__device__ __forceinline__ uint32_t rotl32(uint32_t x, uint32_t n) {
  return (x << n) | (x >> (32u - n));
}

__device__ __forceinline__ uint32_t threefry_draw32(uint32_t j) {
  const uint32_t ks1 = 42u;
  const uint32_t ks2 = 0x1BD11BDAu ^ 42u;  // 0x1BD11BF0
  uint32_t x0 = 0u;        // counts_hi = 0 (+ ks0 = 0)
  uint32_t x1 = j + ks1;   // counts_lo + ks1

#define TFR(r) { x0 += x1; x1 = rotl32(x1, r); x1 ^= x0; }
  TFR(13u) TFR(15u) TFR(26u) TFR(6u)   x0 += ks1; x1 += ks2 + 1u;
  TFR(17u) TFR(29u) TFR(16u) TFR(24u)  x0 += ks2; x1 += 0u  + 2u;
  TFR(13u) TFR(15u) TFR(26u) TFR(6u)   x0 += 0u;  x1 += ks1 + 3u;
  TFR(17u) TFR(29u) TFR(16u) TFR(24u)  x0 += ks1; x1 += ks2 + 4u;
  TFR(13u) TFR(15u) TFR(26u) TFR(6u)   x0 += ks2; x1 += 0u  + 5u;
#undef TFR
  return x0 ^ x1;
}

// ---------------------------------------------------------------------------
// Scalar Cephes/Eigen plog + pexp replicas (XLA:CPU GenerateVF32Log/Exp),
// separate mul/add. Used only by the tiny setup kernel. (Verified round 2.)
// ---------------------------------------------------------------------------
__device__ __forceinline__ float xla_logf(float xin) {
  uint32_t bits = __float_as_uint(xin);
  int emm0 = (int)(bits >> 23) - 0x7f;
  float m = __uint_as_float((bits & 0x007fffffu) | 0x3f000000u);
  float e = (float)emm0 + 1.0f;
  bool mask = m < 0.707106781186547524f;
  float tmp = mask ? m : 0.0f;
  m = m - 1.0f;
  e = e - (mask ? 1.0f : 0.0f);
  m = m + tmp;
  float x2 = m * m;
  float x3 = x2 * m;
  float y  =  7.0376836292e-2f * m + -1.1514610310e-1f;
  float y1 = -1.2420140846e-1f * m +  1.4249322787e-1f;
  float y2 =  2.0000714765e-1f * m + -2.4999993993e-1f;
  y  = y  * m +  1.1676998740e-1f;
  y1 = y1 * m + -1.6668057665e-1f;
  y2 = y2 * m +  3.3333331174e-1f;
  y  = y * x3 + y1;
  y  = y * x3 + y2;
  y  = y * x3;
  float t1 = -2.12194440e-4f * e;
  float t2 = 0.5f * x2;
  y = y + t1;
  m = m - t2;
  float t3 = 0.693359375f * e;
  m = m + y;
  m = m + t3;
  return m;
}

__device__ __forceinline__ float xla_expf(float xin) {
  float xc = fminf(xin, 88.3762626647950f);
  xc = fmaxf(xc, -88.3762626647949f);
  float fx = floorf(xc * 1.44269504088896341f + 0.5f);
  float tmp = 0.693359375f * fx;
  float z   = -2.12194440e-4f * fx;
  float x = xc - tmp;
  x = x - z;
  z = x * x;
  float y = x * 1.9875691500e-4f + 1.3981999507e-3f;
  y = y * x + 8.3334519073e-3f;
  y = y * x + 4.1665795894e-2f;
  y = y * x + 1.6666665459e-1f;
  y = y * x + 5.0000001201e-1f;
  y = y * z + x;
  y = y + 1.0f;
  int n = (int)fx;
  float p2n = __uint_as_float((uint32_t)(n + 0x7f) << 23);
  return fmaxf(y * p2n, xin);
}

// ---------------------------------------------------------------------------
// Packed (2-wide) Cephes plog: identical per-component rounding to xla_logf
// (v_pk_add_f32 / v_pk_mul_f32 are bit-identical IEEE f32 ops; exponent math
// done in exact integer domain then one exact cvt). Valid for positive
// normal inputs.
// ---------------------------------------------------------------------------
__device__ __forceinline__ f32x2 xla_logf_pk(f32x2 xin) {
  uint32_t b0 = __float_as_uint(xin.x);
  uint32_t b1 = __float_as_uint(xin.y);
  f32x2 m;
  m.x = __uint_as_float((b0 & 0x007fffffu) | 0x3f000000u);  // [0.5, 1)
  m.y = __uint_as_float((b1 & 0x007fffffu) | 0x3f000000u);
  bool mk0 = m.x < 0.707106781186547524f;
  bool mk1 = m.y < 0.707106781186547524f;
  // e = (float)((bits>>23) - 127) + 1 - (mask?1:0), computed exactly in ints
  f32x2 e;
  e.x = (float)((int)(b0 >> 23) - 126 - (mk0 ? 1 : 0));
  e.y = (float)((int)(b1 >> 23) - 126 - (mk1 ? 1 : 0));
  f32x2 tmp;
  tmp.x = mk0 ? m.x : 0.0f;
  tmp.y = mk1 ? m.y : 0.0f;
  m = m - 1.0f;
  m = m + tmp;

  f32x2 x2 = m * m;
  f32x2 x3 = x2 * m;

  f32x2 y  = m * 7.0376836292e-2f  + -1.1514610310e-1f;
  f32x2 y1 = m * -1.2420140846e-1f +  1.4249322787e-1f;
  f32x2 y2 = m * 2.0000714765e-1f  + -2.4999993993e-1f;
  y  = y  * m +  1.1676998740e-1f;
  y1 = y1 * m + -1.6668057665e-1f;
  y2 = y2 * m +  3.3333331174e-1f;
  y  = y * x3 + y1;
  y  = y * x3 + y2;
  y  = y * x3;

  f32x2 t1 = e * -2.12194440e-4f;
  f32x2 t2 = x2 * 0.5f;
  y = y + t1;
  m = m - t2;
  f32x2 t3 = e * 0.693359375f;
  m = m + y;
  m = m + t3;
  return m;
}

// Pair of gumbel computations from two raw draws; returns l2 = log(-log(u)).
// Caller forms s = lp - l2  ==  lp + (-l2)  ==  gumbel + logits (bit-exact:
// IEEE add is commutative; subtraction == addition of exact negation).
__device__ __forceinline__ f32x2 log_neg_log_u(uint32_t r0, uint32_t r1) {
  f32x2 f;
  f.x = __uint_as_float((r0 >> 9) | 0x3f800000u);
  f.y = __uint_as_float((r1 >> 9) | 0x3f800000u);
  f = f - 1.0f;                                   // [0, 1)
  f32x2 u;
  u.x = (f.x == 0.0f) ? 1.17549435082228750797e-38f : f.x;  // tiny
  u.y = (f.y == 0.0f) ? 1.17549435082228750797e-38f : f.y;
  f32x2 l1 = xla_logf_pk(u);
  return xla_logf_pk(-l1);                        // negation is exact
}

// ---------------------------------------------------------------------------
// Setup: logp[c*3+a] = log_softmax(W.T + b), same Cephes rounding as the
// reference (verified bit-exact round 2). Writes 6 floats to d_ws.
// ---------------------------------------------------------------------------
__global__ void setup_logp(const float* __restrict__ W,
                           const float* __restrict__ bvec,
                           float* __restrict__ logp) {
  if (threadIdx.x == 0 && blockIdx.x == 0) {
    for (int c = 0; c < 2; ++c) {
      float x0 = W[0 * 2 + c] + bvec[0];
      float x1 = W[1 * 2 + c] + bvec[1];
      float x2 = W[2 * 2 + c] + bvec[2];
      float mx = fmaxf(fmaxf(fmaxf(-__builtin_inff(), x0), x1), x2);
      float s0 = x0 - mx, s1 = x1 - mx, s2 = x2 - mx;
      float e0 = xla_expf(s0);
      float e1 = xla_expf(s1);
      float e2 = xla_expf(s2);
      float se = (e0 + e1) + e2;
      float lse = xla_logf(se);
      logp[c * 3 + 0] = s0 - lse;
      logp[c * 3 + 1] = s1 - lse;
      logp[c * 3 + 2] = s2 - lse;
    }
  }
}

// ---------------------------------------------------------------------------
// Main: one thread per batch element. 6 threefry draws (scalar int) ->
// 3 packed gumbel pairs (draw k for card0 paired with draw k+3 for card1) ->
// per-card argmax (strict >, first max wins) -> u0 / beliefs / log_cf.
// lp pointer is uniform -> scalar loads, no LDS, no barrier.
// ---------------------------------------------------------------------------
__global__ void __launch_bounds__(TPB) sample_kernel(
    const int* __restrict__ cards, const float* __restrict__ lp_g,
    float* __restrict__ out_u0, float* __restrict__ out_beliefs,
    float* __restrict__ out_logcf, int B) {
  int b = blockIdx.x * TPB + threadIdx.x;
  if (b >= B) return;

  float lp[6];
#pragma unroll
  for (int i = 0; i < 6; ++i) lp[i] = lp_g[i];

  uint32_t base = (uint32_t)b * 6u;

  uint32_t r[6];
#pragma unroll
  for (int k = 0; k < 6; ++k) r[k] = threefry_draw32(base + (uint32_t)k);

  // s[k] = gumbel + logits, packed as (card0 action k, card1 action k)
  f32x2 s[3];
#pragma unroll
  for (int k = 0; k < 3; ++k) {
    f32x2 l2 = log_neg_log_u(r[k], r[k + 3]);
    f32x2 lpk;
    lpk.x = lp[k];
    lpk.y = lp[3 + k];
    s[k] = lpk - l2;
  }

  // argmax per card, strict > keeps first occurrence (XLA tie rule)
  int a0 = 0; float best0 = s[0].x;
  if (s[1].x > best0) { best0 = s[1].x; a0 = 1; }
  if (s[2].x > best0) { best0 = s[2].x; a0 = 2; }
  int a1 = 0; float best1 = s[0].y;
  if (s[1].y > best1) { best1 = s[1].y; a1 = 1; }
  if (s[2].y > best1) { best1 = s[2].y; a1 = 2; }

  float lcf0 = lp[a0];
  float lcf1 = lp[3 + a1];

  int card = cards[b];
  int u0 = (card == 0) ? a0 : a1;
  float w0 = (u0 == a0) ? 1.0f : 0.0f;
  float w1 = (u0 == a1) ? 1.0f : 0.0f;
  float half_or_one = ((w0 + w1) > 1.5f) ? 0.5f : 1.0f;  // exact

  out_u0[b] = (float)u0;
  reinterpret_cast<float2*>(out_beliefs)[b] = make_float2(w0 * half_or_one, w1 * half_or_one);
  reinterpret_cast<float2*>(out_logcf)[b]  = make_float2(lcf0, lcf1);
}

extern "C" void kernel_launch(void* const* d_in, const int* in_sizes, int n_in,
                              void* d_out, int out_size, void* d_ws, size_t ws_size,
                              hipStream_t stream) {
  (void)n_in; (void)out_size; (void)ws_size;
  const int* cards = (const int*)d_in[0];   // (B,) int32
  const float* W   = (const float*)d_in[1]; // (3,2) f32 row-major
  const float* bv  = (const float*)d_in[2]; // (3,)  f32
  float* out = (float*)d_out;               // u0[B] | beliefs[B*2] | log_cf[B*2]
  float* lp  = (float*)d_ws;                // 6 floats scratch

  int B = in_sizes[0];
  setup_logp<<<1, 64, 0, stream>>>(W, bv, lp);
  sample_kernel<<<(B + TPB - 1) / TPB, TPB, 0, stream>>>(
      cards, lp, out, out + (size_t)B, out + (size_t)3 * B, B);
}

// Round 4
// 166.051 us; speedup vs baseline: 1.0394x; 1.0133x over previous
//
#include <hip/hip_runtime.h>

// Replicate XLA:CPU's exact f32 rounding: no mul+add fusion anywhere
// (hipcc default is -ffp-contract=fast; XLA:CPU emits separate fmul/fadd
// with xla_cpu_enable_fast_math=false). Applies to packed ops too (blocks
// v_pk_fma formation).
#pragma clang fp contract(off)

#define TPB 256

typedef float f32x2 __attribute__((ext_vector_type(2)));

// ---------------------------------------------------------------------------
// Threefry-2x32, key = (0, 42). Partitionable counting: element j <- block
// (x0 = hi = 0, x1 = lo = j); 32-bit draw = bits1 ^ bits2. (Verified r2/r3.)
// ---------------------------------------------------------------------------
__device__ __forceinline__ uint32_t rotl32(uint32_t x, uint32_t n) {
  return (x << n) | (x >> (32u - n));
}

__device__ __forceinline__ uint32_t threefry_draw32(uint32_t j) {
  const uint32_t ks1 = 42u;
  const uint32_t ks2 = 0x1BD11BDAu ^ 42u;  // 0x1BD11BF0
  uint32_t x0 = 0u;        // counts_hi = 0 (+ ks0 = 0)
  uint32_t x1 = j + ks1;   // counts_lo + ks1

#define TFR(r) { x0 += x1; x1 = rotl32(x1, r); x1 ^= x0; }
  TFR(13u) TFR(15u) TFR(26u) TFR(6u)   x0 += ks1; x1 += ks2 + 1u;
  TFR(17u) TFR(29u) TFR(16u) TFR(24u)  x0 += ks2; x1 += 0u  + 2u;
  TFR(13u) TFR(15u) TFR(26u) TFR(6u)   x0 += 0u;  x1 += ks1 + 3u;
  TFR(17u) TFR(29u) TFR(16u) TFR(24u)  x0 += ks1; x1 += ks2 + 4u;
  TFR(13u) TFR(15u) TFR(26u) TFR(6u)   x0 += ks2; x1 += 0u  + 5u;
#undef TFR
  return x0 ^ x1;
}

// ---------------------------------------------------------------------------
// Scalar Cephes/Eigen plog + pexp replicas (XLA:CPU GenerateVF32Log/Exp),
// separate mul/add. Used only by the tiny setup kernel. (Verified r2.)
// ---------------------------------------------------------------------------
__device__ __forceinline__ float xla_logf(float xin) {
  uint32_t bits = __float_as_uint(xin);
  int emm0 = (int)(bits >> 23) - 0x7f;
  float m = __uint_as_float((bits & 0x007fffffu) | 0x3f000000u);
  float e = (float)emm0 + 1.0f;
  bool mask = m < 0.707106781186547524f;
  float tmp = mask ? m : 0.0f;
  m = m - 1.0f;
  e = e - (mask ? 1.0f : 0.0f);
  m = m + tmp;
  float x2 = m * m;
  float x3 = x2 * m;
  float y  =  7.0376836292e-2f * m + -1.1514610310e-1f;
  float y1 = -1.2420140846e-1f * m +  1.4249322787e-1f;
  float y2 =  2.0000714765e-1f * m + -2.4999993993e-1f;
  y  = y  * m +  1.1676998740e-1f;
  y1 = y1 * m + -1.6668057665e-1f;
  y2 = y2 * m +  3.3333331174e-1f;
  y  = y * x3 + y1;
  y  = y * x3 + y2;
  y  = y * x3;
  float t1 = -2.12194440e-4f * e;
  float t2 = 0.5f * x2;
  y = y + t1;
  m = m - t2;
  float t3 = 0.693359375f * e;
  m = m + y;
  m = m + t3;
  return m;
}

__device__ __forceinline__ float xla_expf(float xin) {
  float xc = fminf(xin, 88.3762626647950f);
  xc = fmaxf(xc, -88.3762626647949f);
  float fx = floorf(xc * 1.44269504088896341f + 0.5f);
  float tmp = 0.693359375f * fx;
  float z   = -2.12194440e-4f * fx;
  float x = xc - tmp;
  x = x - z;
  z = x * x;
  float y = x * 1.9875691500e-4f + 1.3981999507e-3f;
  y = y * x + 8.3334519073e-3f;
  y = y * x + 4.1665795894e-2f;
  y = y * x + 1.6666665459e-1f;
  y = y * x + 5.0000001201e-1f;
  y = y * z + x;
  y = y + 1.0f;
  int n = (int)fx;
  float p2n = __uint_as_float((uint32_t)(n + 0x7f) << 23);
  return fmaxf(y * p2n, xin);
}

// ---------------------------------------------------------------------------
// Packed (2-wide) Cephes plog: per-component rounding identical to xla_logf
// (v_pk ops are bit-identical IEEE f32; exponent math exact in int domain).
// Valid for positive normal inputs. (Verified bit-exact r3.)
// ---------------------------------------------------------------------------
__device__ __forceinline__ f32x2 xla_logf_pk(f32x2 xin) {
  uint32_t b0 = __float_as_uint(xin.x);
  uint32_t b1 = __float_as_uint(xin.y);
  f32x2 m;
  m.x = __uint_as_float((b0 & 0x007fffffu) | 0x3f000000u);  // [0.5, 1)
  m.y = __uint_as_float((b1 & 0x007fffffu) | 0x3f000000u);
  bool mk0 = m.x < 0.707106781186547524f;
  bool mk1 = m.y < 0.707106781186547524f;
  f32x2 e;
  e.x = (float)((int)(b0 >> 23) - 126 - (mk0 ? 1 : 0));
  e.y = (float)((int)(b1 >> 23) - 126 - (mk1 ? 1 : 0));
  f32x2 tmp;
  tmp.x = mk0 ? m.x : 0.0f;
  tmp.y = mk1 ? m.y : 0.0f;
  m = m - 1.0f;
  m = m + tmp;

  f32x2 x2 = m * m;
  f32x2 x3 = x2 * m;

  f32x2 y  = m * 7.0376836292e-2f  + -1.1514610310e-1f;
  f32x2 y1 = m * -1.2420140846e-1f +  1.4249322787e-1f;
  f32x2 y2 = m * 2.0000714765e-1f  + -2.4999993993e-1f;
  y  = y  * m +  1.1676998740e-1f;
  y1 = y1 * m + -1.6668057665e-1f;
  y2 = y2 * m +  3.3333331174e-1f;
  y  = y * x3 + y1;
  y  = y * x3 + y2;
  y  = y * x3;

  f32x2 t1 = e * -2.12194440e-4f;
  f32x2 t2 = x2 * 0.5f;
  y = y + t1;
  m = m - t2;
  f32x2 t3 = e * 0.693359375f;
  m = m + y;
  m = m + t3;
  return m;
}

// l2 = log(-log(u)) for two raw draws. Caller forms s = lp - l2 (bit-exact
// equal to gumbel + logits: add commutative, negation exact).
__device__ __forceinline__ f32x2 log_neg_log_u(uint32_t r0, uint32_t r1) {
  f32x2 f;
  f.x = __uint_as_float((r0 >> 9) | 0x3f800000u);
  f.y = __uint_as_float((r1 >> 9) | 0x3f800000u);
  f = f - 1.0f;                                   // [0, 1)
  f32x2 u;
  u.x = (f.x == 0.0f) ? 1.17549435082228750797e-38f : f.x;  // tiny
  u.y = (f.y == 0.0f) ? 1.17549435082228750797e-38f : f.y;
  f32x2 l1 = xla_logf_pk(u);
  return xla_logf_pk(-l1);
}

// ---------------------------------------------------------------------------
// Setup: logp = log_softmax(W.T + b), same Cephes rounding as reference.
// ---------------------------------------------------------------------------
__global__ void setup_logp(const float* __restrict__ W,
                           const float* __restrict__ bvec,
                           float* __restrict__ logp) {
  if (threadIdx.x == 0 && blockIdx.x == 0) {
    for (int c = 0; c < 2; ++c) {
      float x0 = W[0 * 2 + c] + bvec[0];
      float x1 = W[1 * 2 + c] + bvec[1];
      float x2 = W[2 * 2 + c] + bvec[2];
      float mx = fmaxf(fmaxf(fmaxf(-__builtin_inff(), x0), x1), x2);
      float s0 = x0 - mx, s1 = x1 - mx, s2 = x2 - mx;
      float e0 = xla_expf(s0);
      float e1 = xla_expf(s1);
      float e2 = xla_expf(s2);
      float se = (e0 + e1) + e2;
      float lse = xla_logf(se);
      logp[c * 3 + 0] = s0 - lse;
      logp[c * 3 + 1] = s1 - lse;
      logp[c * 3 + 2] = s2 - lse;
    }
  }
}

// Per-element result bundle.
struct ElemOut {
  float u0, w0, w1, l0, l1;
};

// Full pipeline for batch element b: 6 draws at base=6b -> 3 packed gumbel
// pairs -> per-card argmax (strict >, first max wins) -> outputs.
__device__ __forceinline__ ElemOut process_element(uint32_t b, int card,
                                                   const float lp[6]) {
  uint32_t base = b * 6u;
  uint32_t r[6];
#pragma unroll
  for (int k = 0; k < 6; ++k) r[k] = threefry_draw32(base + (uint32_t)k);

  f32x2 s[3];
#pragma unroll
  for (int k = 0; k < 3; ++k) {
    f32x2 l2 = log_neg_log_u(r[k], r[k + 3]);
    f32x2 lpk;
    lpk.x = lp[k];
    lpk.y = lp[3 + k];
    s[k] = lpk - l2;
  }

  int a0 = 0; float best0 = s[0].x;
  if (s[1].x > best0) { best0 = s[1].x; a0 = 1; }
  if (s[2].x > best0) { best0 = s[2].x; a0 = 2; }
  int a1 = 0; float best1 = s[0].y;
  if (s[1].y > best1) { best1 = s[1].y; a1 = 1; }
  if (s[2].y > best1) { best1 = s[2].y; a1 = 2; }

  ElemOut o;
  o.l0 = lp[a0];
  o.l1 = lp[3 + a1];
  int u0 = (card == 0) ? a0 : a1;
  float w0 = (u0 == a0) ? 1.0f : 0.0f;
  float w1 = (u0 == a1) ? 1.0f : 0.0f;
  float h = ((w0 + w1) > 1.5f) ? 0.5f : 1.0f;  // exact reciprocal of sum
  o.u0 = (float)u0;
  o.w0 = w0 * h;
  o.w1 = w1 * h;
  return o;
}

// ---------------------------------------------------------------------------
// Main: TWO batch elements per thread (b = 2t, 2t+1). Amortizes addressing,
// widens stores to float2/float4/float4, and forces enough live state that
// the allocator can't collapse to 12 VGPRs. Requires B even (BATCH=4194304).
// Output (f32, concat): u0[B] | beliefs[B][2] | log_cf[B][2].
// ---------------------------------------------------------------------------
__global__ void __launch_bounds__(TPB) sample_kernel2(
    const int* __restrict__ cards, const float* __restrict__ lp_g,
    float* __restrict__ out_u0, float* __restrict__ out_beliefs,
    float* __restrict__ out_logcf, int npairs) {
  int t = blockIdx.x * TPB + threadIdx.x;
  if (t >= npairs) return;

  float lp[6];
#pragma unroll
  for (int i = 0; i < 6; ++i) lp[i] = lp_g[i];

  int2 c2 = reinterpret_cast<const int2*>(cards)[t];

  ElemOut e0 = process_element((uint32_t)(2 * t),     c2.x, lp);
  ElemOut e1 = process_element((uint32_t)(2 * t) + 1u, c2.y, lp);

  reinterpret_cast<float2*>(out_u0)[t]      = make_float2(e0.u0, e1.u0);
  reinterpret_cast<float4*>(out_beliefs)[t] = make_float4(e0.w0, e0.w1, e1.w0, e1.w1);
  reinterpret_cast<float4*>(out_logcf)[t]   = make_float4(e0.l0, e0.l1, e1.l0, e1.l1);
}

extern "C" void kernel_launch(void* const* d_in, const int* in_sizes, int n_in,
                              void* d_out, int out_size, void* d_ws, size_t ws_size,
                              hipStream_t stream) {
  (void)n_in; (void)out_size; (void)ws_size;
  const int* cards = (const int*)d_in[0];   // (B,) int32
  const float* W   = (const float*)d_in[1]; // (3,2) f32 row-major
  const float* bv  = (const float*)d_in[2]; // (3,)  f32
  float* out = (float*)d_out;               // u0[B] | beliefs[B*2] | log_cf[B*2]
  float* lp  = (float*)d_ws;                // 6 floats scratch

  int B = in_sizes[0];
  int npairs = B >> 1;  // BATCH = 4194304 (even)
  setup_logp<<<1, 64, 0, stream>>>(W, bv, lp);
  sample_kernel2<<<(npairs + TPB - 1) / TPB, TPB, 0, stream>>>(
      cards, lp, out, out + (size_t)B, out + (size_t)3 * B, npairs);
}